// Round 5
// baseline (794.141 us; speedup 1.0000x reference)
//
#include <hip/hip_runtime.h>
#include <math.h>

#define B 128
#define T 2048
#define H 200
#define G4 800   // 4*H
#define KP 224   // K padded to multiple of 32
#define LROW 224 // LDS row stride (bf16 units) for enc tile
#define NSTG 13  // staging float4 regs per thread (64*50/256 = 12.5)

typedef short short8 __attribute__((ext_vector_type(8)));
typedef float floatx4 __attribute__((ext_vector_type(4)));

__device__ __forceinline__ unsigned short f2bf(float x) {
    unsigned u = __float_as_uint(x);
    return (unsigned short)((u + 0x7fffu + ((u >> 16) & 1u)) >> 16);
}
__device__ __forceinline__ float bf2f(unsigned short s) {
    return __uint_as_float(((unsigned)s) << 16);
}
// pack two floats -> two bf16 (round-nearest-away) in 3 VALU ops
__device__ __forceinline__ unsigned pk2(float a, float b) {
    return __builtin_amdgcn_perm(__float_as_uint(b) + 0x8000u,
                                 __float_as_uint(a) + 0x8000u, 0x07060302u);
}
// tanh(x) = 1 - 2/(exp(2x)+1), hw exp2 + rcp (~1e-6 rel err)
__device__ __forceinline__ float ftanh(float x) {
    float e = __builtin_amdgcn_exp2f(x * 2.885390081777927f);
    float r = __builtin_amdgcn_rcpf(e + 1.f);
    return fmaf(-2.f, r, 1.f);
}
__device__ __forceinline__ float sigm(float x) { return 1.f / (1.f + expf(-x)); }

// ---------------- prep_all ----------------
// blocks 0..255   : Uab row (bf16, zero-padded [256][224])
// blocks 256..383 : qb[b][h] = h0[b] @ Wa.T + ba + bua
// blocks 384..484 : zero ctx_raw + lsum (25728 floats)
__global__ __launch_bounds__(256) void prep_all(const float* __restrict__ Ua,
                                                const float* __restrict__ Wa,
                                                const float* __restrict__ ba,
                                                const float* __restrict__ bua,
                                                const float* __restrict__ h0,
                                                unsigned short* __restrict__ Uab,
                                                float* __restrict__ qb,
                                                float* __restrict__ zbase) {
    __shared__ float qs[H];
    int bx = blockIdx.x, tid = threadIdx.x;
    if (bx < 256) {
        if (tid < KP) {
            float v = (bx < H && tid < H) ? Ua[bx * H + tid] : 0.f;
            Uab[bx * KP + tid] = f2bf(v);
        }
    } else if (bx < 384) {
        int b = bx - 256;
        if (tid < H) qs[tid] = h0[b * H + tid];
        __syncthreads();
        if (tid < H) {
            float a = ba[tid] + bua[tid];
            const float* w = Wa + tid * H;
            #pragma unroll 4
            for (int k = 0; k < H; k++) a = fmaf(qs[k], w[k], a);
            qb[b * H + tid] = a;
        }
    } else {
        int idx = (bx - 384) * 256 + tid;
        if (idx < B * H + B) zbase[idx] = 0.f;
    }
}

// ---------------- fused scores + bounded-softmax + context partials ----------------
// Grid: 1024 blocks = (b, 1/8 of T). Block: 4 chunks of 64 t, register-staged
// software pipeline: load chunk c+1 into VGPRs while MFMA-ing chunk c from LDS.
__global__ __launch_bounds__(256, 4) void scores_ctx(const float* __restrict__ enc,
                                                     const unsigned short* __restrict__ Uab,
                                                     const float* __restrict__ qb,
                                                     const float* __restrict__ Va,
                                                     const float* __restrict__ bva,
                                                     float* __restrict__ ctx_raw,
                                                     float* __restrict__ lsum) {
    __shared__ unsigned short elds[64 * LROW];   // 28672 B
    __shared__ float part[4][64];
    __shared__ float s_qb[256];
    __shared__ float s_va[256];
    __shared__ float wlds[64];
    __shared__ float s_bound;

    int bx    = blockIdx.x;
    int b     = bx >> 3;
    int tbase = (bx & 7) * 256;
    int tid   = threadIdx.x;
    int w     = tid >> 6;
    int lane  = tid & 63;
    int r     = lane & 15;
    int q     = lane >> 4;

    // zero k-pad columns 200..223 once (stay 0: staging never touches them)
    for (int i = tid; i < 64 * 12; i += 256) {
        int rr = i / 12, cc = i - rr * 12;
        *(unsigned*)(elds + rr * LROW + 200 + 2 * cc) = 0u;
    }
    s_qb[tid] = (tid < H) ? qb[b * H + tid] : 0.f;
    s_va[tid] = (tid < H) ? Va[tid] : 0.f;
    float bv = bva[0];

    // tile rows are contiguous in enc: chunk ch = float4 [ch*3200, ch*3200+3200)
    const float4* srcf4 = (const float4*)(enc + ((size_t)(b * T) + tbase) * H);

    float4 reg[NSTG];
    #pragma unroll
    for (int it = 0; it < NSTG; it++) {        // preload chunk 0
        int i = it * 256 + tid;
        if (it < 12 || tid < 128) reg[it] = srcf4[i];
    }

    float lacc = 0.f, ctxacc = 0.f;

    for (int ch = 0; ch < 4; ch++) {
        __syncthreads();   // A: previous chunk's elds consumers done
        #pragma unroll
        for (int it = 0; it < NSTG; it++) {    // pack staged regs -> LDS
            int i = it * 256 + tid;
            if (it < 12 || tid < 128) {
                int rr = i / 50, cc = i - rr * 50;
                unsigned* dst = (unsigned*)(elds + rr * LROW + cc * 4);
                dst[0] = pk2(reg[it].x, reg[it].y);
                dst[1] = pk2(reg[it].z, reg[it].w);
            }
        }
        __syncthreads();   // B: elds ready (iter 0: also s_qb/s_va ready)

        if (ch < 3) {      // issue next chunk's loads; vmcnt waited at next store
            #pragma unroll
            for (int it = 0; it < NSTG; it++) {
                int i = it * 256 + tid;
                if (it < 12 || tid < 128) reg[it] = srcf4[(ch + 1) * 3200 + i];
            }
        }
        if (ch == 0 && tid < 64) {   // score bound = sum|Va| + |bva|
            float a = fabsf(s_va[tid]) + fabsf(s_va[tid + 64]) +
                      fabsf(s_va[tid + 128]) + fabsf(s_va[tid + 192]);
            #pragma unroll
            for (int d = 1; d < 64; d <<= 1) a += __shfl_xor(a, d);
            if (tid == 0) s_bound = a + fabsf(bv);
        }

        float p[4] = {0.f, 0.f, 0.f, 0.f};   // score partials, t = nt*16+r
        for (int mig = 0; mig < 2; ++mig) {
            int m0 = w * 4 + mig * 2;
            short8 af[2][7];
            #pragma unroll
            for (int mi = 0; mi < 2; mi++)
                #pragma unroll
                for (int ks = 0; ks < 7; ks++)
                    af[mi][ks] = *(const short8*)(Uab + ((m0 + mi) * 16 + r) * KP + ks * 32 + q * 8);
            #pragma unroll
            for (int nt = 0; nt < 4; nt++) {
                floatx4 C0 = (floatx4){0.f, 0.f, 0.f, 0.f};
                floatx4 C1 = (floatx4){0.f, 0.f, 0.f, 0.f};
                #pragma unroll
                for (int ks = 0; ks < 7; ks++) {
                    short8 bf = *(const short8*)(elds + (nt * 16 + r) * LROW + ks * 32 + q * 8);
                    C0 = __builtin_amdgcn_mfma_f32_16x16x32_bf16(af[0][ks], bf, C0, 0, 0, 0);
                    C1 = __builtin_amdgcn_mfma_f32_16x16x32_bf16(af[1][ks], bf, C1, 0, 0, 0);
                }
                float pp = 0.f;
                #pragma unroll
                for (int rg = 0; rg < 4; rg++) {
                    int h0i = m0 * 16 + q * 4 + rg;
                    int h1i = h0i + 16;
                    pp += s_va[h0i] * ftanh(s_qb[h0i] + C0[rg]);
                    pp += s_va[h1i] * ftanh(s_qb[h1i] + C1[rg]);
                }
                p[nt] += pp;
            }
        }
        #pragma unroll
        for (int nt = 0; nt < 4; nt++) {
            float pp = p[nt];
            pp += __shfl_xor(pp, 16);
            pp += __shfl_xor(pp, 32);
            if (q == 0) part[w][nt * 16 + r] = pp;
        }
        __syncthreads();   // C: part ready

        if (tid < 64) {    // wave 0: score -> bounded-softmax weight
            float s  = part[0][tid] + part[1][tid] + part[2][tid] + part[3][tid] + bv;
            float we = expf(s - s_bound);
            wlds[tid] = we;
            #pragma unroll
            for (int d = 1; d < 64; d <<= 1) we += __shfl_xor(we, d);
            if (tid == 0) lacc += we;
        }
        __syncthreads();   // D: wlds ready

        if (tid < H) {     // ctx[h] += sum_t w[t]*enc[t,h] from LDS tile
            float a = ctxacc;
            #pragma unroll 4
            for (int t = 0; t < 64; t++)
                a = fmaf(wlds[t], bf2f(elds[t * LROW + tid]), a);
            ctxacc = a;
        }
        // loop-top barrier A protects elds overwrite vs these readers
    }

    if (tid < H)  atomicAdd(&ctx_raw[b * H + tid], ctxacc);
    if (tid == 0) atomicAdd(&lsum[b], lacc);
}

// ---------------- decoder: gates_const inline + 5 steps, one block per batch ----------------
__global__ __launch_bounds__(256) void decoder_all(const float* __restrict__ x,
                                                   const float* __restrict__ h0,
                                                   const float* __restrict__ c0,
                                                   const float* __restrict__ ctx_raw,
                                                   const float* __restrict__ lsum,
                                                   const float* __restrict__ W_ih,
                                                   const float* __restrict__ b_ih,
                                                   const float* __restrict__ W_hh,
                                                   const float* __restrict__ b_hh,
                                                   const float* __restrict__ W1,
                                                   const float* __restrict__ b1,
                                                   const float* __restrict__ W2,
                                                   const float* __restrict__ b2,
                                                   const float* __restrict__ W3,
                                                   const float* __restrict__ b3,
                                                   float* __restrict__ out) {
    int b = blockIdx.x, tid = threadIdx.x;
    __shared__ float s_cat[2 * H];   // [ctx | q]
    __shared__ float s_gc[G4];
    __shared__ float s_wx[G4];
    __shared__ float s_out[H];
    __shared__ float s_o1[100];
    __shared__ float s_o2[50];
    __shared__ float s_x;

    float cprev = 0.f;
    if (tid < H) {
        float invl = 1.f / lsum[b];
        s_cat[tid]     = ctx_raw[b * H + tid] * invl;
        s_cat[H + tid] = h0[b * H + tid];
        cprev          = c0[b * H + tid];
    }
    if (tid == 0) s_x = x[b];
    __syncthreads();

    // gc[j] = b_ih[j]+b_hh[j] + ctx.W_ih[j,1:] + q.W_hh[j,:]  (row-direct, L2-hot)
    for (int j = tid; j < G4; j += 256) {
        const float* wi = W_ih + (size_t)j * (H + 1);
        const float* wh = W_hh + (size_t)j * H;
        float a = b_ih[j] + b_hh[j];
        s_wx[j] = wi[0];
        #pragma unroll 4
        for (int k = 0; k < H; k++)
            a = fmaf(s_cat[k], wi[1 + k], fmaf(s_cat[H + k], wh[k], a));
        s_gc[j] = a;
    }
    __syncthreads();

    for (int s = 0; s < 5; s++) {
        float xv = s_x;
        __syncthreads();
        if (tid < H) {
            float ig = s_gc[tid]         + xv * s_wx[tid];
            float fg = s_gc[H + tid]     + xv * s_wx[H + tid];
            float gg = s_gc[2 * H + tid] + xv * s_wx[2 * H + tid];
            float og = s_gc[3 * H + tid] + xv * s_wx[3 * H + tid];
            float c  = sigm(fg) * cprev + sigm(ig) * tanhf(gg);
            float hn = sigm(og) * tanhf(c);
            s_out[tid] = fmaxf(hn, 0.f);
        }
        __syncthreads();
        if (tid < 100) {
            float a = b1[tid];
            const float* w = W1 + tid * H;
            #pragma unroll 4
            for (int k = 0; k < H; k++) a = fmaf(w[k], s_out[k], a);
            s_o1[tid] = fmaxf(a, 0.f);
        }
        __syncthreads();
        if (tid < 50) {
            float a = b2[tid];
            const float* w = W2 + tid * 100;
            #pragma unroll 4
            for (int k = 0; k < 100; k++) a = fmaf(w[k], s_o1[k], a);
            s_o2[tid] = fmaxf(a, 0.f);
        }
        __syncthreads();
        if (tid < 64) {   // parallel 50-dot + broadcast feedback
            float a = (tid < 50) ? W3[tid] * s_o2[tid] : 0.f;
            #pragma unroll
            for (int d = 1; d < 64; d <<= 1) a += __shfl_xor(a, d);
            if (tid == 0) {
                float y = a + b3[0];
                out[b * 5 + s] = y;
                s_x = y;
            }
        }
        __syncthreads();
    }
}

// ---------------- launch ----------------
extern "C" void kernel_launch(void* const* d_in, const int* in_sizes, int n_in,
                              void* d_out, int out_size, void* d_ws, size_t ws_size,
                              hipStream_t stream) {
    (void)in_sizes; (void)n_in; (void)out_size; (void)ws_size;
    const float* x    = (const float*)d_in[0];
    const float* h0   = (const float*)d_in[1];
    const float* c0   = (const float*)d_in[2];
    const float* enc  = (const float*)d_in[3];
    const float* Wa   = (const float*)d_in[4];
    const float* ba   = (const float*)d_in[5];
    const float* Ua   = (const float*)d_in[6];
    const float* bua  = (const float*)d_in[7];
    const float* Va   = (const float*)d_in[8];
    const float* bva  = (const float*)d_in[9];
    const float* W_ih = (const float*)d_in[10];
    const float* W_hh = (const float*)d_in[11];
    const float* b_ih = (const float*)d_in[12];
    const float* b_hh = (const float*)d_in[13];
    const float* W1   = (const float*)d_in[14];
    const float* b1   = (const float*)d_in[15];
    const float* W2   = (const float*)d_in[16];
    const float* b2   = (const float*)d_in[17];
    const float* W3   = (const float*)d_in[18];
    const float* b3   = (const float*)d_in[19];
    float* out = (float*)d_out;

    char* ws = (char*)d_ws;
    unsigned short* Uab = (unsigned short*)(ws);   // 114688
    float* qb      = (float*)(ws + 114688);        // 102400
    float* ctx_raw = (float*)(ws + 217088);        // 102400
    float* lsum    = (float*)(ws + 319488);        // 512 (contiguous after ctx_raw)

    prep_all<<<dim3(485), 256, 0, stream>>>(Ua, Wa, ba, bua, h0, Uab, qb, ctx_raw);
    scores_ctx<<<dim3(1024), 256, 0, stream>>>(enc, Uab, qb, Va, bva, ctx_raw, lsum);
    decoder_all<<<dim3(B), 256, 0, stream>>>(x, h0, c0, ctx_raw, lsum,
                                             W_ih, b_ih, W_hh, b_hh,
                                             W1, b1, W2, b2, W3, b3, out);
}